// Round 4
// baseline (349.098 us; speedup 1.0000x reference)
//
#include <hip/hip_runtime.h>
#include <hip/hip_cooperative_groups.h>
#include <math.h>

namespace cg = cooperative_groups;

// Problem constants
#define B 64
#define NI 1024
#define NO 1024
#define NC 10
#define GRID 512
#define OT 16        // o's per block in partial phases
#define NSPLIT 8     // i-split across blocks
#define ISEG 128     // i per block
#define WROW 130     // padded LDS row stride (float2 units) -> keeps f4 reads 16B-aligned

typedef float f4 __attribute__((ext_vector_type(4)));
typedef float f2 __attribute__((ext_vector_type(2)));

__device__ __forceinline__ float lt_of(float x) {
    // log(tanh(100*|x|)) clamped: 0-mask * (-1e30) == 0 stays clean; sums may
    // overflow to -inf, exp(-inf)=0 which matches delta==0 exactly.
    return fmaxf(logf(tanhf(100.0f * fabsf(x))), -1e30f);
}

// xl: f4[(NI/2)][B] = (x_i, lt_i, x_{i+1}, lt_{i+1}) per b  (activation pair layout)
// phs: f2[NSPLIT][NO][B] = (h_partial, s_partial)
// Weights go global->LDS pre-masked; inner loop reads them as wave-uniform
// b128 BROADCASTS (bank-conflict-free) while each lane keeps its own b's
// activations from coalesced global f4 loads. FMAs are packed float2.
__device__ __forceinline__ void layer_partial(
    const f4* __restrict__ xl,
    const float* __restrict__ fcw, const float* __restrict__ vw,
    f2* __restrict__ phs, f2* sm)
{
    const int blk = blockIdx.x, t = threadIdx.x;
    const int ot = blk & 63, s = blk >> 6;
    const int o0 = ot * OT, i0 = s * ISEG;

    // ---- stage masked weight pairs: sm[o*WROW + i] = (fc*m, m) ----
    {
        const int o = t >> 4, m8 = (t & 15) * 8;
        const float* fp = &fcw[(o0 + o) * NI + i0 + m8];
        const float* vp = &vw [(o0 + o) * NI + i0 + m8];
        f4 fa = *(const f4*)fp, fb = *(const f4*)(fp + 4);
        f4 va = *(const f4*)vp, vb = *(const f4*)(vp + 4);
        f2* wrow = &sm[o * WROW + m8];
        #pragma unroll
        for (int j = 0; j < 4; ++j) {
            f2 pa; pa.x = va[j] > 0.f ? fa[j] : 0.f; pa.y = va[j] > 0.f ? 1.f : 0.f;
            f2 pb; pb.x = vb[j] > 0.f ? fb[j] : 0.f; pb.y = vb[j] > 0.f ? 1.f : 0.f;
            wrow[j]     = pa;
            wrow[4 + j] = pb;
        }
    }
    __syncthreads();

    // ---- compute: wave w owns i in [w*32, w*32+32), all OT o's; lane = b ----
    const int w = t >> 6, lane = t & 63;
    const int iwb = w * 32;
    f2 acc[OT];
    #pragma unroll
    for (int o = 0; o < OT; ++o) { acc[o].x = 0.f; acc[o].y = 0.f; }

    const f4* xbase = &xl[((i0 + iwb) >> 1) * B + lane];
    #pragma unroll
    for (int ii = 0; ii < 32; ii += 2) {
        f4 xv = xbase[(ii >> 1) * B];      // coalesced, L2-resident
        f2 xa = xv.lo, xb = xv.hi;         // (x_i,lt_i), (x_{i+1},lt_{i+1})
        #pragma unroll
        for (int o = 0; o < OT; ++o) {
            f4 wv = *(const f4*)&sm[o * WROW + iwb + ii];   // uniform addr -> broadcast
            acc[o] = wv.lo * xa + acc[o];   // packed f32 fma: (h += wf*x, s += wm*lt)
            acc[o] = wv.hi * xb + acc[o];
        }
    }
    __syncthreads();   // weights region done; reuse LDS as reduce scratch

    #pragma unroll
    for (int o = 0; o < OT; ++o) sm[(w * OT + o) * B + lane] = acc[o];
    __syncthreads();

    // ---- cross-wave reduce (4 i-subranges) + coalesced partial write ----
    {
        const int o = t >> 4, b4 = (t & 15) * 4;
        f2 r[4];
        #pragma unroll
        for (int bb = 0; bb < 4; ++bb) {
            f2 v0 = sm[(0 * OT + o) * B + b4 + bb];
            f2 v1 = sm[(1 * OT + o) * B + b4 + bb];
            f2 v2 = sm[(2 * OT + o) * B + b4 + bb];
            f2 v3 = sm[(3 * OT + o) * B + b4 + bb];
            r[bb] = (v0 + v1) + (v2 + v3);
        }
        f2* dst = &phs[s * (NO * B) + (o0 + o) * B + b4];
        f4 q0; q0.x = r[0].x; q0.y = r[0].y; q0.z = r[1].x; q0.w = r[1].y;
        f4 q1; q1.x = r[2].x; q1.y = r[2].y; q1.z = r[3].x; q1.w = r[3].y;
        *(f4*)&dst[0] = q0;
        *(f4*)&dst[2] = q1;
    }
}

// finalize 2 o's per thread -> write (h, lt, h', lt') in activation-pair layout
__device__ __forceinline__ void layer_final(
    const f2* __restrict__ phs, f4* __restrict__ xlout, int withlt)
{
    const int g = blockIdx.x * 256 + threadIdx.x;   // caller guards blk < 128
    const int o2 = g >> 6, lane = g & 63;
    f2 s0; s0.x = 0.f; s0.y = 0.f;
    f2 s1 = s0;
    #pragma unroll
    for (int s = 0; s < NSPLIT; ++s) {
        s0 = s0 + phs[s * (NO * B) + (o2 * 2) * B + lane];
        s1 = s1 + phs[s * (NO * B) + (o2 * 2 + 1) * B + lane];
    }
    float h0 = fmaxf(s0.x * expf(s0.y), 0.f);
    float h1 = fmaxf(s1.x * expf(s1.y), 0.f);
    f4 out;
    out.x = h0; out.y = withlt ? lt_of(h0) : 0.f;
    out.z = h1; out.w = withlt ? lt_of(h1) : 0.f;
    xlout[o2 * B + lane] = out;
}

__global__ __launch_bounds__(256, 2) void harsanyi_fused(
    const float* __restrict__ x,
    const float* __restrict__ v0, const float* __restrict__ fc0, const float* __restrict__ hd0,
    const float* __restrict__ v1, const float* __restrict__ fc1, const float* __restrict__ hd1,
    float* __restrict__ y,
    f2* __restrict__ phs, f4* __restrict__ xlA, f4* __restrict__ xlB, f4* __restrict__ xlC)
{
    cg::grid_group grid = cg::this_grid();
    __shared__ f2 smem[4096];   // 32 KB, phase-overlaid
    const int blk = blockIdx.x, t = threadIdx.x;

    // ---- P0: x -> (x, lt) pair layout; block = one b row, coalesced reads ----
    if (blk < B) {
        const int b = blk;
        f4 xq = *(const f4*)&x[b * NI + t * 4];
        f4 o0v, o1v;
        o0v.x = xq.x; o0v.y = lt_of(xq.x); o0v.z = xq.y; o0v.w = lt_of(xq.y);
        o1v.x = xq.z; o1v.y = lt_of(xq.z); o1v.z = xq.w; o1v.w = lt_of(xq.w);
        xlA[(2 * t) * B + b]     = o0v;   // scattered 16B stores, tiny array
        xlA[(2 * t + 1) * B + b] = o1v;
    }
    grid.sync();

    // ---- P1: layer-0 partials ----
    layer_partial(xlA, fc0, v0, phs, smem);
    grid.sync();

    // ---- P2: layer-0 finalize -> xlB = (h0, lt(h0)) pairs ----
    if (blk < 128) layer_final(phs, xlB, 1);
    grid.sync();

    // ---- P3: layer-1 partials ----
    layer_partial(xlB, fc1, v1, phs, smem);
    grid.sync();

    // ---- P4: layer-1 finalize -> xlC = (h1, 0) pairs ----
    if (blk < 128) layer_final(phs, xlC, 0);
    grid.sync();

    // ---- P5: heads. block = class c; head rows staged in LDS, broadcast-read ----
    if (blk < NC) {
        const int c = blk;
        float* hw = (float*)smem;                 // [2][NO]
        *(f4*)&hw[t * 4]      = *(const f4*)&hd0[c * NO + t * 4];
        *(f4*)&hw[NO + t * 4] = *(const f4*)&hd1[c * NO + t * 4];
        __syncthreads();
        const int w = t >> 6, lane = t & 63;
        const int l = w >> 1, half = w & 1;
        const f4* hsrc = l ? xlC : xlB;
        const float* wrow = &hw[l * NO];
        float acc = 0.f;
        const int o2a = half * 256;
        #pragma unroll 4
        for (int o2 = o2a; o2 < o2a + 256; ++o2) {
            f4 h = hsrc[o2 * B + lane];           // coalesced, L2-resident
            f2 wp = *(const f2*)&wrow[o2 * 2];    // uniform addr -> broadcast
            acc = fmaf(h.x, wp.x, fmaf(h.z, wp.y, acc));
        }
        float* red = (float*)smem + 2 * NO;
        __syncthreads();
        red[w * 64 + lane] = acc;
        __syncthreads();
        if (t < B) {
            float sum = red[t] + red[64 + t] + red[128 + t] + red[192 + t];
            y[t * NC + c] = sum;
        }
    }
}

extern "C" void kernel_launch(void* const* d_in, const int* in_sizes, int n_in,
                              void* d_out, int out_size, void* d_ws, size_t ws_size,
                              hipStream_t stream) {
    const float* x   = (const float*)d_in[0];
    const float* v0  = (const float*)d_in[1];
    const float* fc0 = (const float*)d_in[2];
    const float* hd0 = (const float*)d_in[3];
    const float* v1  = (const float*)d_in[4];
    const float* fc1 = (const float*)d_in[5];
    const float* hd1 = (const float*)d_in[6];
    float* y = (float*)d_out;

    f2* phs = (f2*)d_ws;                          // 8*1024*64 f2 = 4 MB
    f4* xlA = (f4*)(phs + NSPLIT * NO * B);       // 512 KB each
    f4* xlB = xlA + (NI / 2) * B;
    f4* xlC = xlB + (NO / 2) * B;

    void* args[] = {(void*)&x, (void*)&v0, (void*)&fc0, (void*)&hd0,
                    (void*)&v1, (void*)&fc1, (void*)&hd1, (void*)&y,
                    (void*)&phs, (void*)&xlA, (void*)&xlB, (void*)&xlC};
    hipLaunchCooperativeKernel((const void*)harsanyi_fused, dim3(GRID), dim3(256),
                               args, 0, stream);
}

// Round 5
// 47.377 us; speedup vs baseline: 7.3685x; 7.3685x over previous
//
#include <hip/hip_runtime.h>
#include <math.h>

// Problem constants
#define B 64
#define NI 1024
#define NO 1024
#define NC 10
#define ISPLIT 16
#define ISEG 64        // NI / ISPLIT
#define OT 32          // o's per block
#define OW 8           // o's per wave (4 waves x 8 = 32)
#define WPAD 2         // smw row pad (keeps 16B align, spreads banks)

typedef float f4 __attribute__((ext_vector_type(4)));
typedef float f2 __attribute__((ext_vector_type(2)));

__device__ __forceinline__ float lt_of(float x) {
    // log(tanh(100*|x|)) clamped: exp(sum) reproduces the masked product;
    // x==0 -> -1e30 -> exp -> 0 exactly; 0-mask * (-1e30) = 0 stays clean.
    return fmaxf(logf(tanhf(100.0f * fabsf(x))), -1e30f);
}

// Partial sums for one layer over i-segment `is`:
//   phs[is][o][b] = ( sum_i x[b,i]*fc[o,i]*m[o,i],  sum_i lt[b,i]*m[o,i] )
// FIRST: input is raw x [B][NI], lt computed in-kernel (fused prep).
// else : input is pair layout xpair f4[NI/2][B] = (h,lt,h',lt').
template<bool FIRST>
__global__ __launch_bounds__(256, 2) void partial_k(
    const float* __restrict__ xraw,
    const f4*    __restrict__ xpair,
    const float* __restrict__ fc, const float* __restrict__ v,
    f2* __restrict__ phs)
{
    const int blk = blockIdx.x, t = threadIdx.x;
    const int ob = blk & 31, is = blk >> 5;
    const int o0 = ob * OT, i0 = is * ISEG;
    const int w = t >> 6, lane = t & 63;

    __shared__ f2 smw[OT][ISEG + WPAD];  // pre-masked (fc*m, m) pairs, ~17 KB
    __shared__ f4 smx[ISEG / 2][B];      // (x,lt,x',lt') pair rows, 32 KB

    // ---- stage masked weight pairs: 8 threads per o-row, coalesced f4 ----
    {
        const int o = t >> 3, i8 = (t & 7) * 8;
        const float* fp = &fc[(o0 + o) * NI + i0 + i8];
        const float* vp = &v [(o0 + o) * NI + i0 + i8];
        f4 fa = *(const f4*)fp, fb = *(const f4*)(fp + 4);
        f4 va = *(const f4*)vp, vb = *(const f4*)(vp + 4);
        #pragma unroll
        for (int j = 0; j < 4; ++j) {
            f2 pa; pa.x = va[j] > 0.f ? fa[j] : 0.f; pa.y = va[j] > 0.f ? 1.f : 0.f;
            f2 pb; pb.x = vb[j] > 0.f ? fb[j] : 0.f; pb.y = vb[j] > 0.f ? 1.f : 0.f;
            smw[o][i8 + j]     = pa;
            smw[o][i8 + 4 + j] = pb;
        }
    }
    // ---- stage activation pairs: wave w covers i-slice [w*16, w*16+16) ----
    if (FIRST) {
        const float* xr = &xraw[lane * NI + i0 + w * 16];
        #pragma unroll
        for (int q = 0; q < 4; ++q) {          // 4 x f4 = 16 i per lane
            f4 xq = *(const f4*)&xr[q * 4];
            f4 r0, r1;
            r0.x = xq.x; r0.y = lt_of(xq.x); r0.z = xq.y; r0.w = lt_of(xq.y);
            r1.x = xq.z; r1.y = lt_of(xq.z); r1.z = xq.w; r1.w = lt_of(xq.w);
            smx[w * 8 + q * 2][lane]     = r0;
            smx[w * 8 + q * 2 + 1][lane] = r1;
        }
    } else {
        #pragma unroll
        for (int r = 0; r < 8; ++r)
            smx[w * 8 + r][lane] = xpair[(i0 / 2 + w * 8 + r) * B + lane];
    }
    __syncthreads();

    // ---- compute: wave w owns o in [w*8, w*8+8), full 64-i segment ----
    f2 acc[OW];
    #pragma unroll
    for (int oo = 0; oo < OW; ++oo) { acc[oo].x = 0.f; acc[oo].y = 0.f; }

    #pragma unroll
    for (int pr = 0; pr < ISEG / 2; ++pr) {
        f4 xv = smx[pr][lane];                        // per-lane b128, conflict-free
        #pragma unroll
        for (int oo = 0; oo < OW; ++oo) {
            f4 wv = *(const f4*)&smw[w * OW + oo][pr * 2];  // uniform addr -> broadcast
            acc[oo] = wv.lo * xv.lo + acc[oo];   // packed: (h += wf*x, s += wm*lt)
            acc[oo] = wv.hi * xv.hi + acc[oo];
        }
    }
    #pragma unroll
    for (int oo = 0; oo < OW; ++oo)
        phs[(is * NO + o0 + w * OW + oo) * B + lane] = acc[oo];   // coalesced 512B
}

// Reduce splits, finalize h = relu(sh*exp(ss)), emit pair layout f4[(o/2)][b].
template<bool WITHLT>
__global__ __launch_bounds__(256) void final_k(
    const f2* __restrict__ phs, f4* __restrict__ xp)
{
    const int t = threadIdx.x;
    const int o2 = blockIdx.x * 4 + (t >> 6), lane = t & 63;
    f2 se; se.x = 0.f; se.y = 0.f;
    f2 so = se;
    #pragma unroll
    for (int s = 0; s < ISPLIT; ++s) {
        se = se + phs[(s * NO + 2 * o2)     * B + lane];
        so = so + phs[(s * NO + 2 * o2 + 1) * B + lane];
    }
    float he = fmaxf(se.x * expf(se.y), 0.f);
    float ho = fmaxf(so.x * expf(so.y), 0.f);
    f4 r;
    r.x = he; r.y = WITHLT ? lt_of(he) : 0.f;
    r.z = ho; r.w = WITHLT ? lt_of(ho) : 0.f;
    xp[o2 * B + lane] = r;
}

// y[b][c] = sum_o h0[o][b]*hd0[c][o] + h1[o][b]*hd1[c][o].  Block = class c.
__global__ __launch_bounds__(256) void head_k(
    const f4* __restrict__ xpB, const f4* __restrict__ xpC,
    const float* __restrict__ hd0, const float* __restrict__ hd1,
    float* __restrict__ y)
{
    const int c = blockIdx.x, t = threadIdx.x;
    __shared__ float hw[2 * NO];
    __shared__ float red[256];
    *(f4*)&hw[t * 4]      = *(const f4*)&hd0[c * NO + t * 4];
    *(f4*)&hw[NO + t * 4] = *(const f4*)&hd1[c * NO + t * 4];
    __syncthreads();
    const int w = t >> 6, lane = t & 63;
    float acc = 0.f;
    #pragma unroll
    for (int l = 0; l < 2; ++l) {
        const f4* xp = l ? xpC : xpB;
        const float* hh = &hw[l * NO];
        #pragma unroll 8
        for (int o2 = w * 128; o2 < w * 128 + 128; ++o2) {
            f4 hp = xp[o2 * B + lane];              // coalesced, L2-resident
            f2 wp = *(const f2*)&hh[o2 * 2];        // uniform -> broadcast
            acc = fmaf(hp.x, wp.x, fmaf(hp.z, wp.y, acc));
        }
    }
    red[t] = acc;
    __syncthreads();
    if (t < B) y[t * NC + c] = red[t] + red[64 + t] + red[128 + t] + red[192 + t];
}

extern "C" void kernel_launch(void* const* d_in, const int* in_sizes, int n_in,
                              void* d_out, int out_size, void* d_ws, size_t ws_size,
                              hipStream_t stream) {
    const float* x   = (const float*)d_in[0];
    const float* v0  = (const float*)d_in[1];
    const float* fc0 = (const float*)d_in[2];
    const float* hd0 = (const float*)d_in[3];
    const float* v1  = (const float*)d_in[4];
    const float* fc1 = (const float*)d_in[5];
    const float* hd1 = (const float*)d_in[6];
    float* y = (float*)d_out;

    f2* phs = (f2*)d_ws;                           // 16*1024*64 f2 = 8 MB
    f4* xpB = (f4*)(phs + ISPLIT * NO * B);        // (h0, lt1) pairs, 512 KB
    f4* xpC = xpB + (NO / 2) * B;                  // (h1, 0) pairs, 512 KB

    partial_k<true ><<<512, 256, 0, stream>>>(x, nullptr, fc0, v0, phs);
    final_k  <true ><<<128, 256, 0, stream>>>(phs, xpB);
    partial_k<false><<<512, 256, 0, stream>>>(nullptr, xpB, fc1, v1, phs);
    final_k  <false><<<128, 256, 0, stream>>>(phs, xpC);
    head_k          <<<NC,  256, 0, stream>>>(xpB, xpC, hd0, hd1, y);
}

// Round 6
// 41.981 us; speedup vs baseline: 8.3156x; 1.1285x over previous
//
#include <hip/hip_runtime.h>
#include <math.h>

// Problem constants
#define B 64
#define NI 1024
#define NO 1024
#define NC 10
#define ISPLIT 16
#define ISEG 64      // NI / ISPLIT
#define OT 32        // o's per block in partial kernels

typedef float    f4  __attribute__((ext_vector_type(4)));
typedef float    f2  __attribute__((ext_vector_type(2)));
typedef _Float16 h2v __attribute__((ext_vector_type(2)));

__device__ __forceinline__ float lt_of(float x) {
    // log(tanh(100|x|)); sentinel -6e4 (not -1e30) so f16 partial sums of
    // multiple sentinels overflow to -inf -> exp(-inf)=0, matching delta==0.
    return fmaxf(logf(tanhf(100.0f * fabsf(x))), -60000.0f);
}

// phs[is][o][b] = f16x2( sum_i x*fc*m , sum_i lt*m ) over i-segment `is`.
// Thread = 2 b x 4 o cells: per 2-i step 6 ds_read_b128 feed 16 pk_fma.
template<bool FIRST>
__global__ __launch_bounds__(256, 2) void partial_k(
    const float* __restrict__ xraw,      // [B][NI]   (FIRST)
    const f2*    __restrict__ xp,        // [NO][B] (h,lt) (!FIRST)
    const float* __restrict__ fc,
    const float* __restrict__ v,
    h2v* __restrict__ phs)               // [ISPLIT][NO][B]
{
    const int blk = blockIdx.x, t = threadIdx.x;
    const int ob = blk & 31, is = blk >> 5;
    const int o0 = ob * OT, i0 = is * ISEG;

    __shared__ f4 xs[ISEG / 2][B];       // [i2][b] = (x,lt,x',lt')   32 KB
    __shared__ f4 w4[ISEG][OT / 2];      // [i][o2] = (wf,wm,wf',wm') 16 KB

    // ---- stage masked weights: 8 threads per o-row, coalesced f4 loads ----
    {
        const int o = t >> 3, i8 = (t & 7) * 8;
        const float* fp = &fc[(o0 + o) * NI + i0 + i8];
        const float* vp = &v [(o0 + o) * NI + i0 + i8];
        f4 fa = *(const f4*)fp, fb = *(const f4*)(fp + 4);
        f4 va = *(const f4*)vp, vb = *(const f4*)(vp + 4);
        #pragma unroll
        for (int j = 0; j < 4; ++j) {
            f2 pa; pa.x = va[j] > 0.f ? fa[j] : 0.f; pa.y = va[j] > 0.f ? 1.f : 0.f;
            ((f2*)&w4[i8 + j][o >> 1])[o & 1] = pa;
            f2 pb; pb.x = vb[j] > 0.f ? fb[j] : 0.f; pb.y = vb[j] > 0.f ? 1.f : 0.f;
            ((f2*)&w4[i8 + 4 + j][o >> 1])[o & 1] = pb;
        }
    }
    // ---- stage activation pairs: thread covers 8 i2-rows of its b ----
    {
        const int b = t & 63, r = t >> 6;
        if (FIRST) {
            const float* xr = &xraw[b * NI + i0 + r * 16];
            #pragma unroll
            for (int q = 0; q < 4; ++q) {        // 64B contiguous per lane
                f4 xq = *(const f4*)&xr[q * 4];
                f4 e0, e1;
                e0.x = xq.x; e0.y = lt_of(xq.x); e0.z = xq.y; e0.w = lt_of(xq.y);
                e1.x = xq.z; e1.y = lt_of(xq.z); e1.z = xq.w; e1.w = lt_of(xq.w);
                xs[r * 8 + q * 2][b]     = e0;
                xs[r * 8 + q * 2 + 1][b] = e1;
            }
        } else {
            #pragma unroll
            for (int q = 0; q < 8; ++q) {        // coalesced 8B loads
                int i = i0 + (r * 8 + q) * 2;
                f2 lo = xp[i * B + b];
                f2 hi = xp[(i + 1) * B + b];
                f4 e; e.x = lo.x; e.y = lo.y; e.z = hi.x; e.w = hi.y;
                xs[r * 8 + q][b] = e;
            }
        }
    }
    __syncthreads();

    // ---- compute: bg = b-pair (2 b), og = o-quad (4 o) ----
    const int bg = t & 31, og = t >> 5;
    f2 acc[4][2];
    #pragma unroll
    for (int k = 0; k < 4; ++k) { acc[k][0] = (f2)0.f; acc[k][1] = (f2)0.f; }

    #pragma unroll
    for (int s2 = 0; s2 < ISEG / 2; ++s2) {
        f4 xa = xs[s2][bg * 2];              // lane's b even: (x,lt | x',lt')
        f4 xb = xs[s2][bg * 2 + 1];          // b odd
        f4 w0 = w4[s2 * 2][og * 2];          // i even, o {0,1}
        f4 w1 = w4[s2 * 2][og * 2 + 1];      // i even, o {2,3}
        f4 w2 = w4[s2 * 2 + 1][og * 2];      // i odd
        f4 w3 = w4[s2 * 2 + 1][og * 2 + 1];
        acc[0][0] = w0.xy * xa.xy + acc[0][0];  acc[0][1] = w0.xy * xb.xy + acc[0][1];
        acc[1][0] = w0.zw * xa.xy + acc[1][0];  acc[1][1] = w0.zw * xb.xy + acc[1][1];
        acc[2][0] = w1.xy * xa.xy + acc[2][0];  acc[2][1] = w1.xy * xb.xy + acc[2][1];
        acc[3][0] = w1.zw * xa.xy + acc[3][0];  acc[3][1] = w1.zw * xb.xy + acc[3][1];
        acc[0][0] = w2.xy * xa.zw + acc[0][0];  acc[0][1] = w2.xy * xb.zw + acc[0][1];
        acc[1][0] = w2.zw * xa.zw + acc[1][0];  acc[1][1] = w2.zw * xb.zw + acc[1][1];
        acc[2][0] = w3.xy * xa.zw + acc[2][0];  acc[2][1] = w3.xy * xb.zw + acc[2][1];
        acc[3][0] = w3.zw * xa.zw + acc[3][0];  acc[3][1] = w3.zw * xb.zw + acc[3][1];
    }
    #pragma unroll
    for (int k = 0; k < 4; ++k)
        #pragma unroll
        for (int b2 = 0; b2 < 2; ++b2) {
            h2v hv; hv.x = (_Float16)acc[k][b2].x; hv.y = (_Float16)acc[k][b2].y;
            phs[(is * NO + o0 + og * 4 + k) * B + bg * 2 + b2] = hv;
        }
}

// Reduce splits, h0 = relu(sh*exp(ss)), emit (h0, lt(h0)); also zero y.
__global__ __launch_bounds__(256) void final0_k(
    const h2v* __restrict__ phs, f2* __restrict__ xpB, float* __restrict__ y)
{
    const int t = threadIdx.x;
    if (blockIdx.x == 0 && t < (B * NC) / 4) {
        f4 z; z.x = 0.f; z.y = 0.f; z.z = 0.f; z.w = 0.f;
        ((f4*)y)[t] = z;
    }
    const int g = blockIdx.x * 256 + t;
    const int o = g >> 6, b = g & 63;
    f2 s; s.x = 0.f; s.y = 0.f;
    #pragma unroll
    for (int sp = 0; sp < ISPLIT; ++sp) {
        h2v p = phs[(sp * NO + o) * B + b];
        s.x += (float)p.x; s.y += (float)p.y;
    }
    float h = fmaxf(s.x * expf(s.y), 0.f);
    f2 r; r.x = h; r.y = lt_of(h);
    xpB[o * B + b] = r;
}

// Fused: finalize layer-1 (reduce+exp) for an o-range, then both heads,
// atomicAdd into y (zeroed by final0_k). Grid = 16 blocks x 64 o.
__global__ __launch_bounds__(256) void head_k(
    const h2v* __restrict__ phs, const f2* __restrict__ xpB,
    const float* __restrict__ hd0, const float* __restrict__ hd1,
    float* __restrict__ y)
{
    const int blk = blockIdx.x, t = threadIdx.x;
    const int o0 = blk * 64;
    __shared__ f2 hh[64][B];        // (h0, h1)   32 KB
    __shared__ f2 hdl[NC][64];      // (hd0, hd1)  5 KB

    for (int rep = 0; rep < 16; ++rep) {
        int cell = t + rep * 256;
        int ol = cell >> 6, b = cell & 63;
        f2 s; s.x = 0.f; s.y = 0.f;
        #pragma unroll
        for (int sp = 0; sp < ISPLIT; ++sp) {
            h2v p = phs[(sp * NO + o0 + ol) * B + b];
            s.x += (float)p.x; s.y += (float)p.y;
        }
        float h1 = fmaxf(s.x * expf(s.y), 0.f);
        f2 e; e.x = xpB[(o0 + ol) * B + b].x; e.y = h1;
        hh[ol][b] = e;
    }
    for (int e = t; e < NC * 64; e += 256) {
        int c = e >> 6, ol = e & 63;
        f2 d; d.x = hd0[c * NO + o0 + ol]; d.y = hd1[c * NO + o0 + ol];
        hdl[c][ol] = d;
    }
    __syncthreads();

    const int w = t >> 6, lane = t & 63;
    for (int cc = w; cc < NC; cc += 4) {
        float acc = 0.f;
        #pragma unroll 8
        for (int ol = 0; ol < 64; ++ol) {
            f2 hv = hh[ol][lane];           // stride-256B column: conflict-free
            f2 dv = hdl[cc][ol];            // wave-uniform broadcast
            acc = fmaf(hv.x, dv.x, fmaf(hv.y, dv.y, acc));
        }
        atomicAdd(&y[lane * NC + cc], acc);
    }
}

extern "C" void kernel_launch(void* const* d_in, const int* in_sizes, int n_in,
                              void* d_out, int out_size, void* d_ws, size_t ws_size,
                              hipStream_t stream) {
    const float* x   = (const float*)d_in[0];
    const float* v0  = (const float*)d_in[1];
    const float* fc0 = (const float*)d_in[2];
    const float* hd0 = (const float*)d_in[3];
    const float* v1  = (const float*)d_in[4];
    const float* fc1 = (const float*)d_in[5];
    const float* hd1 = (const float*)d_in[6];
    float* y = (float*)d_out;

    h2v* phs = (h2v*)d_ws;                         // 16*1024*64*4B = 4 MB
    f2*  xpB = (f2*)((char*)d_ws + (size_t)ISPLIT * NO * B * sizeof(h2v));  // 512 KB

    partial_k<true ><<<512, 256, 0, stream>>>(x, nullptr, fc0, v0, phs);
    final0_k        <<<256, 256, 0, stream>>>(phs, xpB, y);
    partial_k<false><<<512, 256, 0, stream>>>(nullptr, xpB, fc1, v1, phs);
    head_k          <<<16,  256, 0, stream>>>(phs, xpB, hd0, hd1, y);
}